// Round 5
// baseline (425.826 us; speedup 1.0000x reference)
//
#include <hip/hip_runtime.h>

#define NROWS 8192
#define NCOLS 8192
#define LD    8193          // matching_scores row stride (8193x8193 input)
#define NBINS 64
#define KCORR 2048
#define MAXC  8192
#define CAP   192           // candidate bucket capacity per row (mean ~55)
// Fast-path cut: v <= exp(m)*1 <= 0.08  =>  cannot exceed t41 (~0.09).
// Bins 0..41 stay bit-exact; crossing expected at n* ~ 33.
#define FCUT_LOG (-2.5257286443082556f)   // ln(0.08)

// inner value EXACTLY as the reference: p = ref_i * src_j; v = exp(m) * p
__device__ __forceinline__ float inner_val(float m, float rr, float sc) {
    float p = rr * sc;
    return expf(m) * p;
}

// Fill outputs with invalid-slot values; zero hist.
__global__ void init_kernel(float* __restrict__ out, unsigned* __restrict__ hist) {
    int i = blockIdx.x * blockDim.x + threadIdx.x;
    if (i < 2 * MAXC)       out[i] = -1.0f;   // ref/src index fill
    else if (i < 3 * MAXC)  out[i] = 0.0f;    // score fill
    if (i < NBINS) hist[i] = 0u;
}

// Exact slow-path binning + candidate append.
__device__ __forceinline__ void slow_bin(float m, float rr, float sc, int col,
                                         const float* t, unsigned* sub,
                                         unsigned* s_cnt, unsigned* ccol,
                                         float* cval, int use_cand) {
    float v = inner_val(m, rr, sc);
    int g = (int)floorf((0.5f - v) * 100.0f) + 1;
    g = (g < 0) ? 0 : ((g > NBINS) ? NBINS : g);
    while (g < NBINS && t[g] >= v) ++g;
    while (g > 0 && t[g - 1] < v) --g;
    atomicAdd(&sub[g], 1u);
    if (use_cand) {
        unsigned slot = atomicAdd(s_cnt, 1u);
        if (slot < CAP) { ccol[slot] = (unsigned)col; cval[slot] = v; }
    }
}

// One block per TWO rows. Each thread issues 16 independent float4 loads
// (256 B in flight) before any consumption; ~0.7% of elements take the
// slow path (exact expf + bin + candidate emit). Epilogue: waves 0/1 do
// the two rows' bin prefix scans concurrently; cumulative counts stored
// transposed (rowhistT[bin*NROWS+row]).
__global__ __launch_bounds__(256) void hist_kernel(
    const float* __restrict__ ms, const float* __restrict__ refs,
    const float* __restrict__ srcs, unsigned* __restrict__ hist,
    unsigned* __restrict__ rowhistT, int use_rowhist,
    unsigned* __restrict__ candcnt, unsigned* __restrict__ cand_col,
    float* __restrict__ cand_v, int use_cand)
{
    __shared__ float t[NBINS];
    __shared__ unsigned sub[2][NBINS];
    __shared__ unsigned s_cnt[2];
    int tid = threadIdx.x;
    if (tid == 0) {  // replicate the reference's float32 threshold fold
        float tv = 0.5f;
        for (int n = 0; n < NBINS; ++n) { t[n] = tv; tv = tv - 0.01f; }
    }
    if (tid < 2 * NBINS) sub[tid >> 6][tid & 63] = 0u;
    if (tid < 2) s_cnt[tid] = 0u;
    __syncthreads();

    int r0 = blockIdx.x * 2;
    float rrA = refs[r0], rrB = refs[r0 + 1];
    const float* mrowA = ms + (size_t)r0 * LD;
    const float* mrowB = mrowA + LD;
    unsigned* ccolA = cand_col + (size_t)r0 * CAP;
    unsigned* ccolB = ccolA + CAP;
    float* cvalA = cand_v + (size_t)r0 * CAP;
    float* cvalB = cvalA + CAP;

    // alignment peel: (row*8193) mod 4 == row mod 4
    int sA = (4 - (r0 & 3)) & 3;
    int sB = (4 - ((r0 + 1) & 3)) & 3;
    const float4* a4 = (const float4*)(mrowA + sA);
    const float4* b4 = (const float4*)(mrowB + sB);
    int nbA = (NCOLS - sA) >> 2;   // 2048 or 2047
    int nbB = (NCOLS - sB) >> 2;

    // ---- issue all 16 vector loads before ANY consumption ----
    float4 qa[8], qb[8];
    #pragma unroll
    for (int k = 0; k < 8; ++k) {   // k<7 always in range (tid+1792 <= 2047)
        int i = tid + 256 * k;
        if (k < 7 || i < nbA) qa[k] = a4[i];
        else qa[k] = make_float4(-1e30f, -1e30f, -1e30f, -1e30f);
    }
    #pragma unroll
    for (int k = 0; k < 8; ++k) {
        int i = tid + 256 * k;
        if (k < 7 || i < nbB) qb[k] = b4[i];
        else qb[k] = make_float4(-1e30f, -1e30f, -1e30f, -1e30f);
    }

    // ---- peels (<=3 scalar lanes per row) ----
    if (tid < sA) {
        float m = mrowA[tid];
        if (m > FCUT_LOG)
            slow_bin(m, rrA, srcs[tid], tid, t, sub[0], &s_cnt[0], ccolA, cvalA, use_cand);
    }
    if (tid < sB) {
        float m = mrowB[tid];
        if (m > FCUT_LOG)
            slow_bin(m, rrB, srcs[tid], tid, t, sub[1], &s_cnt[1], ccolB, cvalB, use_cand);
    }

    // ---- consume row A ----
    #pragma unroll
    for (int k = 0; k < 8; ++k) {
        int c0 = sA + 4 * (tid + 256 * k);
        bool any = (qa[k].x > FCUT_LOG) | (qa[k].y > FCUT_LOG) |
                   (qa[k].z > FCUT_LOG) | (qa[k].w > FCUT_LOG);
        if (any) {
            if (qa[k].x > FCUT_LOG) slow_bin(qa[k].x, rrA, srcs[c0 + 0], c0 + 0, t, sub[0], &s_cnt[0], ccolA, cvalA, use_cand);
            if (qa[k].y > FCUT_LOG) slow_bin(qa[k].y, rrA, srcs[c0 + 1], c0 + 1, t, sub[0], &s_cnt[0], ccolA, cvalA, use_cand);
            if (qa[k].z > FCUT_LOG) slow_bin(qa[k].z, rrA, srcs[c0 + 2], c0 + 2, t, sub[0], &s_cnt[0], ccolA, cvalA, use_cand);
            if (qa[k].w > FCUT_LOG) slow_bin(qa[k].w, rrA, srcs[c0 + 3], c0 + 3, t, sub[0], &s_cnt[0], ccolA, cvalA, use_cand);
        }
    }
    // ---- consume row B ----
    #pragma unroll
    for (int k = 0; k < 8; ++k) {
        int c0 = sB + 4 * (tid + 256 * k);
        bool any = (qb[k].x > FCUT_LOG) | (qb[k].y > FCUT_LOG) |
                   (qb[k].z > FCUT_LOG) | (qb[k].w > FCUT_LOG);
        if (any) {
            if (qb[k].x > FCUT_LOG) slow_bin(qb[k].x, rrB, srcs[c0 + 0], c0 + 0, t, sub[1], &s_cnt[1], ccolB, cvalB, use_cand);
            if (qb[k].y > FCUT_LOG) slow_bin(qb[k].y, rrB, srcs[c0 + 1], c0 + 1, t, sub[1], &s_cnt[1], ccolB, cvalB, use_cand);
            if (qb[k].z > FCUT_LOG) slow_bin(qb[k].z, rrB, srcs[c0 + 2], c0 + 2, t, sub[1], &s_cnt[1], ccolB, cvalB, use_cand);
            if (qb[k].w > FCUT_LOG) slow_bin(qb[k].w, rrB, srcs[c0 + 3], c0 + 3, t, sub[1], &s_cnt[1], ccolB, cvalB, use_cand);
        }
    }
    // ---- tails (<=3 elements per row) ----
    {
        int doneA = sA + (nbA << 2);
        if (tid < NCOLS - doneA) {
            int c = doneA + tid;
            float m = mrowA[c];
            if (m > FCUT_LOG)
                slow_bin(m, rrA, srcs[c], c, t, sub[0], &s_cnt[0], ccolA, cvalA, use_cand);
        }
        int doneB = sB + (nbB << 2);
        if (tid < NCOLS - doneB) {
            int c = doneB + tid;
            float m = mrowB[c];
            if (m > FCUT_LOG)
                slow_bin(m, rrB, srcs[c], c, t, sub[1], &s_cnt[1], ccolB, cvalB, use_cand);
        }
    }
    __syncthreads();

    if (tid < 128) {   // waves 0/1: per-row prefix over bins, store transposed
        int wv = tid >> 6, lane = tid & 63;
        int row = r0 + wv;
        unsigned v = sub[wv][lane];
        unsigned p = v;
        #pragma unroll
        for (int off = 1; off < 64; off <<= 1) {
            unsigned u = __shfl_up(p, off);
            if (lane >= off) p += u;
        }
        unsigned slowtot = __shfl(p, 63);
        if (use_rowhist)
            rowhistT[(size_t)lane * NROWS + row] = (lane == 63) ? (unsigned)NCOLS : p;
        unsigned g = (lane == 63) ? (v + (unsigned)NCOLS - slowtot) : v;
        if (g) atomicAdd(&hist[lane], g);
    } else if (tid < 130 && use_cand) {
        candcnt[r0 + (tid - 128)] = s_cnt[tid - 128];
    }
}

// Threshold selection + rowoff scan in one 1-block launch.
__global__ __launch_bounds__(1024) void mid_kernel(
    const unsigned* __restrict__ hist, const unsigned* __restrict__ rowhistT,
    float* __restrict__ thres, unsigned* __restrict__ nstar,
    unsigned* __restrict__ rowoff, int use_rowhist)
{
    __shared__ int s_ns;
    __shared__ unsigned ssum[1024];
    int tid = threadIdx.x;
    if (tid < 64) {
        unsigned h = hist[tid];
        unsigned cum = h;
        #pragma unroll
        for (int off = 1; off < 64; off <<= 1) {
            unsigned u = __shfl_up(cum, off);
            if (tid >= off) cum += u;
        }
        unsigned long long mk = __ballot(cum >= (unsigned)KCORR);
        int nsel = mk ? (int)(__ffsll((unsigned long long)mk) - 1) : (NBINS - 1);
        if (tid == 0) {
            float tv = 0.5f;                      // replicate the float fold
            for (int n = 0; n < nsel; ++n) tv = tv - 0.01f;
            *thres = tv;
            *nstar = (unsigned)nsel;
            s_ns = nsel;
        }
    }
    __syncthreads();
    if (!use_rowhist) return;   // fallback kernels will build rowoff
    int ns = s_ns;
    const unsigned* rc = rowhistT + (size_t)ns * NROWS;
    int r0 = tid * 8;
    unsigned c[8], s = 0;
    #pragma unroll
    for (int k = 0; k < 8; ++k) { c[k] = rc[r0 + k]; s += c[k]; }
    ssum[tid] = s;
    __syncthreads();
    for (int off = 1; off < 1024; off <<= 1) {
        unsigned v = (tid >= off) ? ssum[tid - off] : 0u;
        __syncthreads();
        ssum[tid] += v;
        __syncthreads();
    }
    unsigned excl = ssum[tid] - s;
    #pragma unroll
    for (int k = 0; k < 8; ++k) { rowoff[r0 + k] = excl; excl += c[k]; }
    if (tid == 1023) rowoff[NROWS] = excl;
}

// Recount fallback: only runs if rowoff from rowhistT is invalid
// (!use_rowhist, or 42<=ns<63 where fast-path pollution breaks bins).
__global__ __launch_bounds__(256) void count2_kernel(
    const float* __restrict__ ms, const float* __restrict__ refs,
    const float* __restrict__ srcs, const float* __restrict__ thresp,
    const unsigned* __restrict__ nstar, unsigned* __restrict__ rowcnt,
    int use_rowhist)
{
    int ns = (int)*nstar;
    if (use_rowhist && !(ns >= 42 && ns < 63)) return;  // uniform fast exit
    __shared__ unsigned tot;
    float th = *thresp;
    for (int r4 = 0; r4 < 4; ++r4) {
        int row = blockIdx.x * 4 + r4;
        if (threadIdx.x == 0) tot = 0;
        __syncthreads();
        float rr = refs[row];
        const float* mrow = ms + (size_t)row * LD;
        unsigned cnt = 0;
        for (int c = threadIdx.x; c < NCOLS; c += 256)
            cnt += (inner_val(mrow[c], rr, srcs[c]) > th) ? 1u : 0u;
        atomicAdd(&tot, cnt);
        __syncthreads();
        if (threadIdx.x == 0) rowcnt[row] = tot;
        __syncthreads();
    }
}

__global__ __launch_bounds__(1024) void scan2_kernel(
    const unsigned* __restrict__ rowcnt, const unsigned* __restrict__ nstar,
    unsigned* __restrict__ rowoff, int use_rowhist)
{
    int ns = (int)*nstar;
    if (use_rowhist && !(ns >= 42 && ns < 63)) return;
    __shared__ unsigned ssum[1024];
    int tid = threadIdx.x;
    int r0 = tid * 8;
    unsigned c[8], s = 0;
    for (int k = 0; k < 8; ++k) { c[k] = rowcnt[r0 + k]; s += c[k]; }
    ssum[tid] = s;
    __syncthreads();
    for (int off = 1; off < 1024; off <<= 1) {
        unsigned v = (tid >= off) ? ssum[tid - off] : 0u;
        __syncthreads();
        ssum[tid] += v;
        __syncthreads();
    }
    unsigned excl = ssum[tid] - s;
    for (int k = 0; k < 8; ++k) { rowoff[r0 + k] = excl; excl += c[k]; }
    if (tid == 1023) rowoff[NROWS] = excl;
}

// One wave per row; candidate path touches NO matrix data: filter <=CAP
// candidates by v>th, rank survivors by col (exact row-major order), write.
// Full-scan fallback per row when candidates are unusable.
__global__ __launch_bounds__(256) void cwrite_kernel(
    const float* __restrict__ ms, const float* __restrict__ refs,
    const float* __restrict__ srcs, const float* __restrict__ thresp,
    const unsigned* __restrict__ nstar, const unsigned* __restrict__ rowoff,
    const unsigned* __restrict__ candcnt, const unsigned* __restrict__ cand_col,
    const float* __restrict__ cand_v, float* __restrict__ out, int use_cand)
{
    __shared__ unsigned s_col[4][64];
    __shared__ float    s_val[4][64];
    int tid = threadIdx.x, wv = tid >> 6, lane = tid & 63;
    int row = blockIdx.x * 4 + wv;
    unsigned base = rowoff[row], next = rowoff[row + 1];
    if (base == next || base >= MAXC) return;   // wave-uniform exit
    float th = *thresp;
    int ns = (int)*nstar;
    unsigned k = next - base;
    bool full = (!use_cand) || (ns >= 42) || (candcnt[row] > CAP) || (k > 64);

    if (!full) {
        unsigned C = candcnt[row];
        const unsigned* cc = cand_col + (size_t)row * CAP;
        const float*    cv = cand_v  + (size_t)row * CAP;
        unsigned nrun = 0;
        for (unsigned c0 = 0; c0 < C; c0 += 64) {
            unsigned i = c0 + lane;
            bool sel = false; unsigned col = 0; float v = 0.f;
            if (i < C) { col = cc[i]; v = cv[i]; sel = (v > th); }
            unsigned long long mk = __ballot(sel);
            if (sel) {
                unsigned idx = nrun + (unsigned)__popcll(mk & ((1ull << lane) - 1ull));
                if (idx < 64) { s_col[wv][idx] = col; s_val[wv][idx] = v; }
            }
            nrun += (unsigned)__popcll(mk);
        }
        __builtin_amdgcn_s_waitcnt(0);       // drain LDS writes
        __builtin_amdgcn_wave_barrier();     // block compiler reordering
        unsigned kk = (nrun < k) ? nrun : k;
        if (kk > 64) kk = 64;
        if (lane < (int)kk) {
            unsigned mycol = s_col[wv][lane];
            float    myval = s_val[wv][lane];
            unsigned rank = 0;
            for (unsigned j = 0; j < kk; ++j)
                rank += (s_col[wv][j] < mycol) ? 1u : 0u;
            unsigned pos = base + rank;
            if (pos < MAXC) {
                out[pos]            = (float)row;
                out[MAXC + pos]     = (float)mycol;
                out[2 * MAXC + pos] = myval;
            }
        }
        return;
    }

    // full-row ordered ballot scan (cold path; correct for any input)
    float rr = refs[row];
    const float* mrow = ms + (size_t)row * LD;
    unsigned running = base;
    for (int c0 = 0; c0 < NCOLS && running < next && running < MAXC; c0 += 64) {
        int col = c0 + lane;
        float v = inner_val(mrow[col], rr, srcs[col]);
        bool pred = v > th;
        unsigned long long mk = __ballot(pred);
        if (pred) {
            unsigned pos = running + (unsigned)__popcll(mk & ((1ull << lane) - 1ull));
            if (pos < MAXC) {
                out[pos]            = (float)row;
                out[MAXC + pos]     = (float)col;
                out[2 * MAXC + pos] = v;
            }
        }
        running += (unsigned)__popcll(mk);
    }
}

extern "C" void kernel_launch(void* const* d_in, const int* in_sizes, int n_in,
                              void* d_out, int out_size, void* d_ws, size_t ws_size,
                              hipStream_t stream) {
    const float* ms  = (const float*)d_in[0];  // 8193x8193
    const float* ref = (const float*)d_in[1];  // 8192
    const float* src = (const float*)d_in[2];  // 8192
    float* out = (float*)d_out;                // [refIdx | srcIdx | scores] as f32

    char* w = (char*)d_ws;
    unsigned* hist   = (unsigned*)(w);                    // 64 u32
    float*    thres  = (float*)(w + 256);
    unsigned* nstar  = (unsigned*)(w + 260);
    unsigned* rowcnt = (unsigned*)(w + 512);              // 8192 u32 (fallback)
    unsigned* rowoff = (unsigned*)(w + 512 + NROWS * 4);  // 8193 u32
    size_t rh_off = 512 + (size_t)NROWS * 4 + (size_t)(NROWS + 1) * 4;
    rh_off = (rh_off + 255) & ~(size_t)255;
    unsigned* rowhistT = (unsigned*)(w + rh_off);         // 64*8192 u32 = 2 MB
    size_t cc_off = rh_off + (size_t)NBINS * NROWS * 4;
    unsigned* candcnt  = (unsigned*)(w + cc_off);         // 8192 u32
    size_t col_off = cc_off + (size_t)NROWS * 4;
    unsigned* cand_col = (unsigned*)(w + col_off);        // 8192*CAP u32
    size_t cv_off = col_off + (size_t)NROWS * CAP * 4;
    float* cand_v      = (float*)(w + cv_off);            // 8192*CAP f32
    size_t end_off = cv_off + (size_t)NROWS * CAP * 4;

    int use_rowhist = (ws_size >= cc_off) ? 1 : 0;
    int use_cand    = (ws_size >= end_off) ? 1 : 0;   // implies use_rowhist

    init_kernel<<<96, 256, 0, stream>>>(out, hist);
    hist_kernel<<<NROWS / 2, 256, 0, stream>>>(ms, ref, src, hist, rowhistT,
                                               use_rowhist, candcnt, cand_col,
                                               cand_v, use_cand);
    mid_kernel<<<1, 1024, 0, stream>>>(hist, rowhistT, thres, nstar, rowoff,
                                       use_rowhist);
    count2_kernel<<<NROWS / 4, 256, 0, stream>>>(ms, ref, src, thres, nstar,
                                                 rowcnt, use_rowhist);
    scan2_kernel<<<1, 1024, 0, stream>>>(rowcnt, nstar, rowoff, use_rowhist);
    cwrite_kernel<<<NROWS / 4, 256, 0, stream>>>(ms, ref, src, thres, nstar,
                                                 rowoff, candcnt, cand_col,
                                                 cand_v, out, use_cand);
}

// Round 6
// 382.712 us; speedup vs baseline: 1.1127x; 1.1127x over previous
//
#include <hip/hip_runtime.h>

#define NROWS 8192
#define NCOLS 8192
#define LD    8193          // matching_scores row stride (8193x8193 input)
#define NBINS 64
#define KCORR 2048
#define MAXC  8192
#define CAP   192           // candidate bucket capacity per row (mean ~55)
#define RPB   4             // rows per hist block (2048 blocks -> 8 blocks/CU)
// Fast-path cut: v <= exp(m)*1 <= 0.08  =>  cannot exceed t41 (~0.09).
// Bins 0..41 stay bit-exact; crossing expected at n* ~ 33.
#define FCUT_LOG (-2.5257286443082556f)   // ln(0.08)

// inner value EXACTLY as the reference: p = ref_i * src_j; v = exp(m) * p
__device__ __forceinline__ float inner_val(float m, float rr, float sc) {
    float p = rr * sc;
    return expf(m) * p;
}

// Fill outputs with invalid-slot values; zero hist + flags.
__global__ void init_kernel(float* __restrict__ out, unsigned* __restrict__ hist,
                            unsigned* __restrict__ ovfl) {
    int i = blockIdx.x * blockDim.x + threadIdx.x;
    if (i < 2 * MAXC)       out[i] = -1.0f;   // ref/src index fill
    else if (i < 3 * MAXC)  out[i] = 0.0f;    // score fill
    if (i < NBINS) hist[i] = 0u;
    if (i == NBINS) *ovfl = 0u;
}

// Streaming hist. Hot loop: double-buffered 4xfloat4 batches, pipelined
// (issue batch b+1, then consume batch b) so loads stay in flight
// continuously. Slow lanes (~0.7%) only append (col, m-bits) to an LDS
// bucket. Epilogue (once per block): expf + exact t[]-binning of the LDS
// pairs, global hist atomic, coalesced candidate writes.
__global__ __launch_bounds__(256) void hist_kernel(
    const float* __restrict__ ms, const float* __restrict__ refs,
    const float* __restrict__ srcs, unsigned* __restrict__ hist,
    unsigned* __restrict__ candcnt, unsigned* __restrict__ cand_col,
    float* __restrict__ cand_v, unsigned* __restrict__ ovfl, int use_cand)
{
    __shared__ float t[NBINS];
    __shared__ unsigned sub[NBINS];
    __shared__ unsigned cnt[RPB];
    __shared__ uint2 pairs[RPB * CAP];
    int tid = threadIdx.x;
    if (tid == 0) {  // replicate the reference's float32 threshold fold
        float tv = 0.5f;
        for (int n = 0; n < NBINS; ++n) { t[n] = tv; tv = tv - 0.01f; }
    }
    if (tid < NBINS) sub[tid] = 0u;
    if (tid < RPB) cnt[tid] = 0u;
    __syncthreads();

    int r0 = blockIdx.x * RPB;

    auto push = [&](int r, int col, float m) {
        unsigned slot = atomicAdd(&cnt[r], 1u);
        if (slot < CAP)
            pairs[r * CAP + slot] = make_uint2((unsigned)col, __float_as_uint(m));
    };
    // batch b: row = b>>1, half = b&1; covers float4 idx half*1024 + k*256 + tid
    auto issue = [&](int b, float4* dst) {
        int r = b >> 1, h = b & 1;
        int row = r0 + r;
        int s = (4 - (row & 3)) & 3;                 // (row*8193) mod 4 == row mod 4
        const float4* p4 = (const float4*)(ms + (size_t)row * LD + s);
        int nb = (NCOLS - s) >> 2;                   // 2048 (s==0) or 2047
        #pragma unroll
        for (int k = 0; k < 4; ++k) {
            int i = h * 1024 + k * 256 + tid;
            if ((h == 1 && k == 3) ? (i < nb) : true) dst[k] = p4[i];
            else dst[k] = make_float4(-1e30f, -1e30f, -1e30f, -1e30f);
        }
    };
    auto consume = [&](int b, const float4* src4) {
        int r = b >> 1, h = b & 1;
        int s = (4 - ((r0 + r) & 3)) & 3;
        #pragma unroll
        for (int k = 0; k < 4; ++k) {
            float4 q = src4[k];
            int c0 = s + 4 * (h * 1024 + k * 256 + tid);
            bool a0 = q.x > FCUT_LOG, a1 = q.y > FCUT_LOG;
            bool a2 = q.z > FCUT_LOG, a3 = q.w > FCUT_LOG;
            if (a0 | a1 | a2 | a3) {   // rare (~2.7% of quads)
                if (a0) push(r, c0 + 0, q.x);
                if (a1) push(r, c0 + 1, q.y);
                if (a2) push(r, c0 + 2, q.z);
                if (a3) push(r, c0 + 3, q.w);
            }
        }
    };

    float4 buf[2][4];
    issue(0, buf[0]);
    #pragma unroll
    for (int b = 0; b < 2 * RPB; ++b) {
        if (b + 1 < 2 * RPB) issue(b + 1, buf[(b + 1) & 1]);
        consume(b, buf[b & 1]);
    }

    // peel/tail pickup: <=4 scalar elements per row, fully parallel
    if (tid < RPB * 8) {
        int r = tid >> 3, e = tid & 7;
        int row = r0 + r;
        int s = (4 - (row & 3)) & 3;
        int nb = (NCOLS - s) >> 2;
        int done = s + 4 * nb;
        int col = -1;
        if (e < s) col = e;
        else if (e - s < NCOLS - done) col = done + (e - s);
        if (col >= 0) {
            float m = ms[(size_t)row * LD + col];
            if (m > FCUT_LOG) push(r, col, m);
        }
    }
    __syncthreads();

    // epilogue: exact binning + candidate emission from LDS pairs
    for (int r = 0; r < RPB; ++r) {
        int row = r0 + r;
        unsigned C = cnt[r];
        unsigned Cc = (C < CAP) ? C : CAP;
        float rr = refs[row];
        for (unsigned i = tid; i < Cc; i += 256) {
            uint2 pr = pairs[r * CAP + i];
            int col = (int)pr.x;
            float m = __uint_as_float(pr.y);
            float v = inner_val(m, rr, srcs[col]);
            int g = (int)floorf((0.5f - v) * 100.0f) + 1;   // guess
            g = (g < 0) ? 0 : ((g > NBINS) ? NBINS : g);
            while (g < NBINS && t[g] >= v) ++g;             // verify (<=1 step)
            while (g > 0 && t[g - 1] < v) --g;
            atomicAdd(&sub[g], 1u);
            if (use_cand) {
                cand_col[(size_t)row * CAP + i] = (unsigned)col;
                cand_v[(size_t)row * CAP + i]   = v;
            }
        }
        if (tid == 0) {
            if (use_cand) candcnt[row] = C;
            if (C > CAP) atomicOr(ovfl, 1u);   // bins unreliable -> full fallback
        }
    }
    __syncthreads();

    if (tid < 64) {   // block-level hist -> global; fast+overflow mass -> bin 63
        unsigned v = sub[tid];
        unsigned p = v;
        #pragma unroll
        for (int off = 1; off < 64; off <<= 1) {
            unsigned u = __shfl_up(p, off);
            if (tid >= off) p += u;
        }
        unsigned binned = __shfl(p, 63);
        unsigned g = (tid == 63) ? (v + (unsigned)(RPB * NCOLS) - binned) : v;
        if (g) atomicAdd(&hist[tid], g);
    }
}

// Threshold selection (exact replay of the while-loop on cumulative bins).
__global__ void mid_kernel(const unsigned* __restrict__ hist,
                           float* __restrict__ thres, unsigned* __restrict__ nstar) {
    int tid = threadIdx.x;
    if (tid < 64) {
        unsigned h = hist[tid];
        unsigned cum = h;
        #pragma unroll
        for (int off = 1; off < 64; off <<= 1) {
            unsigned u = __shfl_up(cum, off);
            if (tid >= off) cum += u;
        }
        unsigned long long mk = __ballot(cum >= (unsigned)KCORR);
        int nsel = mk ? (int)(__ffsll((unsigned long long)mk) - 1) : (NBINS - 1);
        if (tid == 0) {
            float tv = 0.5f;                      // replicate the float fold
            for (int n = 0; n < nsel; ++n) tv = tv - 0.01f;
            *thres = tv;
            *nstar = (unsigned)nsel;
        }
    }
}

// Per-row count from candidates (valid path). One wave per row.
__global__ __launch_bounds__(256) void rowcnt_kernel(
    const float* __restrict__ ms, const float* __restrict__ refs,
    const float* __restrict__ srcs, const float* __restrict__ thresp,
    const unsigned* __restrict__ nstar, const unsigned* __restrict__ ovfl,
    const unsigned* __restrict__ candcnt, const float* __restrict__ cand_v,
    unsigned* __restrict__ rowcnt, int use_cand)
{
    int ns = (int)*nstar;
    if (!(use_cand && ns <= 41 && *ovfl == 0u)) return;   // count2 will handle
    int tid = threadIdx.x, wv = tid >> 6, lane = tid & 63;
    int row = blockIdx.x * 4 + wv;
    float th = *thresp;
    unsigned C = candcnt[row];
    unsigned c = 0;
    if (C <= CAP) {
        const float* cv = cand_v + (size_t)row * CAP;
        for (unsigned i = lane; i < C; i += 64)
            c += (cv[i] > th) ? 1u : 0u;
    } else {   // bucket overflow (practically never): full row scan
        float rr = refs[row];
        const float* mrow = ms + (size_t)row * LD;
        for (int col = lane; col < NCOLS; col += 64)
            c += (inner_val(mrow[col], rr, srcs[col]) > th) ? 1u : 0u;
    }
    #pragma unroll
    for (int off = 32; off > 0; off >>= 1) c += __shfl_down(c, off);
    if (lane == 0) rowcnt[row] = c;
}

// Full recount fallback (runs only when the candidate path is invalid).
__global__ __launch_bounds__(256) void count2_kernel(
    const float* __restrict__ ms, const float* __restrict__ refs,
    const float* __restrict__ srcs, const float* __restrict__ thresp,
    const unsigned* __restrict__ nstar, const unsigned* __restrict__ ovfl,
    unsigned* __restrict__ rowcnt, int use_cand)
{
    int ns = (int)*nstar;
    if (use_cand && ns <= 41 && *ovfl == 0u) return;   // uniform fast exit
    __shared__ unsigned tot;
    float th = *thresp;
    for (int r4 = 0; r4 < 4; ++r4) {
        int row = blockIdx.x * 4 + r4;
        if (threadIdx.x == 0) tot = 0;
        __syncthreads();
        float rr = refs[row];
        const float* mrow = ms + (size_t)row * LD;
        unsigned c = 0;
        for (int col = threadIdx.x; col < NCOLS; col += 256)
            c += (inner_val(mrow[col], rr, srcs[col]) > th) ? 1u : 0u;
        atomicAdd(&tot, c);
        __syncthreads();
        if (threadIdx.x == 0) rowcnt[row] = tot;
        __syncthreads();
    }
}

// Exclusive prefix over 8192 row counts (single block; always runs).
__global__ __launch_bounds__(1024) void scan_kernel(
    const unsigned* __restrict__ rowcnt, unsigned* __restrict__ rowoff)
{
    __shared__ unsigned ssum[1024];
    int tid = threadIdx.x;
    int r0 = tid * 8;
    unsigned c[8], s = 0;
    #pragma unroll
    for (int k = 0; k < 8; ++k) { c[k] = rowcnt[r0 + k]; s += c[k]; }
    ssum[tid] = s;
    __syncthreads();
    for (int off = 1; off < 1024; off <<= 1) {
        unsigned v = (tid >= off) ? ssum[tid - off] : 0u;
        __syncthreads();
        ssum[tid] += v;
        __syncthreads();
    }
    unsigned excl = ssum[tid] - s;
    #pragma unroll
    for (int k = 0; k < 8; ++k) { rowoff[r0 + k] = excl; excl += c[k]; }
    if (tid == 1023) rowoff[NROWS] = excl;
}

// One wave per row; candidate path touches NO matrix data: filter <=CAP
// candidates by v>th, rank survivors by col (exact row-major order), write.
// Full-scan fallback per row when candidates are unusable.
__global__ __launch_bounds__(256) void cwrite_kernel(
    const float* __restrict__ ms, const float* __restrict__ refs,
    const float* __restrict__ srcs, const float* __restrict__ thresp,
    const unsigned* __restrict__ nstar, const unsigned* __restrict__ ovfl,
    const unsigned* __restrict__ rowoff, const unsigned* __restrict__ candcnt,
    const unsigned* __restrict__ cand_col, const float* __restrict__ cand_v,
    float* __restrict__ out, int use_cand)
{
    __shared__ unsigned s_col[4][64];
    __shared__ float    s_val[4][64];
    int tid = threadIdx.x, wv = tid >> 6, lane = tid & 63;
    int row = blockIdx.x * 4 + wv;
    unsigned base = rowoff[row], next = rowoff[row + 1];
    if (base == next || base >= MAXC) return;   // wave-uniform exit
    float th = *thresp;
    int ns = (int)*nstar;
    unsigned k = next - base;
    bool full = (!use_cand) || (ns >= 42) || (*ovfl != 0u) ||
                (candcnt[row] > CAP) || (k > 64);

    if (!full) {
        unsigned C = candcnt[row];
        const unsigned* cc = cand_col + (size_t)row * CAP;
        const float*    cv = cand_v  + (size_t)row * CAP;
        unsigned nrun = 0;
        for (unsigned c0 = 0; c0 < C; c0 += 64) {
            unsigned i = c0 + lane;
            bool sel = false; unsigned col = 0; float v = 0.f;
            if (i < C) { col = cc[i]; v = cv[i]; sel = (v > th); }
            unsigned long long mk = __ballot(sel);
            if (sel) {
                unsigned idx = nrun + (unsigned)__popcll(mk & ((1ull << lane) - 1ull));
                if (idx < 64) { s_col[wv][idx] = col; s_val[wv][idx] = v; }
            }
            nrun += (unsigned)__popcll(mk);
        }
        __builtin_amdgcn_s_waitcnt(0);       // drain LDS writes
        __builtin_amdgcn_wave_barrier();     // block compiler reordering
        unsigned kk = (nrun < k) ? nrun : k;
        if (kk > 64) kk = 64;
        if (lane < (int)kk) {
            unsigned mycol = s_col[wv][lane];
            float    myval = s_val[wv][lane];
            unsigned rank = 0;
            for (unsigned j = 0; j < kk; ++j)
                rank += (s_col[wv][j] < mycol) ? 1u : 0u;
            unsigned pos = base + rank;
            if (pos < MAXC) {
                out[pos]            = (float)row;
                out[MAXC + pos]     = (float)mycol;
                out[2 * MAXC + pos] = myval;
            }
        }
        return;
    }

    // full-row ordered ballot scan (cold path; correct for any input)
    float rr = refs[row];
    const float* mrow = ms + (size_t)row * LD;
    unsigned running = base;
    for (int c0 = 0; c0 < NCOLS && running < next && running < MAXC; c0 += 64) {
        int col = c0 + lane;
        float v = inner_val(mrow[col], rr, srcs[col]);
        bool pred = v > th;
        unsigned long long mk = __ballot(pred);
        if (pred) {
            unsigned pos = running + (unsigned)__popcll(mk & ((1ull << lane) - 1ull));
            if (pos < MAXC) {
                out[pos]            = (float)row;
                out[MAXC + pos]     = (float)col;
                out[2 * MAXC + pos] = v;
            }
        }
        running += (unsigned)__popcll(mk);
    }
}

extern "C" void kernel_launch(void* const* d_in, const int* in_sizes, int n_in,
                              void* d_out, int out_size, void* d_ws, size_t ws_size,
                              hipStream_t stream) {
    const float* ms  = (const float*)d_in[0];  // 8193x8193
    const float* ref = (const float*)d_in[1];  // 8192
    const float* src = (const float*)d_in[2];  // 8192
    float* out = (float*)d_out;                // [refIdx | srcIdx | scores] as f32

    char* w = (char*)d_ws;
    unsigned* hist   = (unsigned*)(w);                    // 64 u32
    float*    thres  = (float*)(w + 256);
    unsigned* nstar  = (unsigned*)(w + 260);
    unsigned* ovfl   = (unsigned*)(w + 264);
    unsigned* rowcnt = (unsigned*)(w + 512);              // 8192 u32
    unsigned* rowoff = (unsigned*)(w + 512 + NROWS * 4);  // 8193 u32
    size_t cc_off = 512 + (size_t)NROWS * 4 + (size_t)(NROWS + 1) * 4;
    cc_off = (cc_off + 255) & ~(size_t)255;
    unsigned* candcnt  = (unsigned*)(w + cc_off);         // 8192 u32
    size_t col_off = cc_off + (size_t)NROWS * 4;
    unsigned* cand_col = (unsigned*)(w + col_off);        // 8192*CAP u32
    size_t cv_off = col_off + (size_t)NROWS * CAP * 4;
    float* cand_v      = (float*)(w + cv_off);            // 8192*CAP f32
    size_t end_off = cv_off + (size_t)NROWS * CAP * 4;    // ~12.7 MB total

    int use_cand = (ws_size >= end_off) ? 1 : 0;

    init_kernel<<<96, 256, 0, stream>>>(out, hist, ovfl);
    hist_kernel<<<NROWS / RPB, 256, 0, stream>>>(ms, ref, src, hist, candcnt,
                                                 cand_col, cand_v, ovfl, use_cand);
    mid_kernel<<<1, 64, 0, stream>>>(hist, thres, nstar);
    rowcnt_kernel<<<NROWS / 4, 256, 0, stream>>>(ms, ref, src, thres, nstar,
                                                 ovfl, candcnt, cand_v, rowcnt,
                                                 use_cand);
    count2_kernel<<<NROWS / 4, 256, 0, stream>>>(ms, ref, src, thres, nstar,
                                                 ovfl, rowcnt, use_cand);
    scan_kernel<<<1, 1024, 0, stream>>>(rowcnt, rowoff);
    cwrite_kernel<<<NROWS / 4, 256, 0, stream>>>(ms, ref, src, thres, nstar,
                                                 ovfl, rowoff, candcnt, cand_col,
                                                 cand_v, out, use_cand);
}